// Round 13
// baseline (535.954 us; speedup 1.0000x reference)
//
#include <hip/hip_runtime.h>
#include <hip/hip_bf16.h>
#include <math.h>

// GPT forward: V=50257, B=16, T=256, D=64, H=4, HS=16, L=4, F=256
constexpr int NV  = 50257;
constexpr int NB  = 16;
constexpr int NT  = 256;
constexpr int ND  = 64;
constexpr int NH  = 4;
constexpr int NHS = 16;
constexpr int NL  = 4;
constexpr int NF  = 256;
constexpr int NN  = NB * NT;        // 4096 rows
constexpr float EPS = 1e-5f;

constexpr int NCB2 = 200;                    // head col blocks of 256 (8-divisible)
constexpr int NVP  = NCB2 * 256;             // 51200 padded vocab
constexpr int LOGITS = NN * NV;              // 205,852,672
constexpr int RB_N  = NN / 64;               // 64 row blocks
constexpr int CB_PER_XCD = NCB2 / 8;         // 25

// workspace layout (float offsets)
constexpr int X_OFF   = 0;                        // [NN*ND] f32
constexpr int Q_OFF   = X_OFF  + NN * ND;         // bf16 [B,H,T,HS]
constexpr int K_OFF   = Q_OFF  + NN * ND;
constexpr int V_OFF   = K_OFF  + NN * ND;
constexpr int O_OFF   = V_OFF  + NN * ND;         // f32 [NN][64]
constexpr int A_OFF   = O_OFF  + NN * ND;         // (spacer)
constexpr int XFB_OFF = A_OFF  + NN * NF;         // bf16 [NN*ND]
constexpr int WM_OFF  = XFB_OFF + NN * ND / 2;    // (spacer)
constexpr int WS2_OFF = WM_OFF + 200 * NN;        // [NCB2*NN] sum-exp partials
constexpr int WHB_OFF = WS2_OFF + 200 * NN;       // bf16 [NVP*64]
constexpr int LP_OFF  = WHB_OFF + NVP * 32;       // [NN]

typedef __bf16 bf16x8 __attribute__((ext_vector_type(8)));
typedef float  f32x4  __attribute__((ext_vector_type(4)));

// ---------------- embed + LN1 + QKV (layer 0 only; 16 rows/block, 256 blocks) ----------------
__global__ __launch_bounds__(256) void k_ln_qkv(
        float* __restrict__ x, const float* __restrict__ g, const float* __restrict__ bb,
        const float* __restrict__ Wq, const float* __restrict__ Wk, const float* __restrict__ Wv,
        __hip_bfloat16* __restrict__ q, __hip_bfloat16* __restrict__ k,
        __hip_bfloat16* __restrict__ v,
        const int* __restrict__ idx, const float* __restrict__ tok,
        const float* __restrict__ pos) {
    __shared__ float hs[16][65];
    int t = threadIdx.x;
    int r0 = blockIdx.x * 16;
    for (int i = t; i < 16 * 64; i += 256) {
        int n = r0 + (i >> 6);
        int tt = n & (NT - 1), d = i & 63;
        float e = tok[idx[n] * ND + d] + pos[tt * ND + d];
        hs[i >> 6][i & 63] = e;
        x[(size_t)r0 * 64 + i] = e;
    }
    __syncthreads();
    {
        int row = t >> 4, sub = t & 15;
        float s = 0.f, s2 = 0.f;
        #pragma unroll
        for (int j = 0; j < 4; j++) { float vv = hs[row][sub * 4 + j]; s += vv; s2 += vv * vv; }
        #pragma unroll
        for (int off = 1; off < 16; off <<= 1) { s += __shfl_xor(s, off); s2 += __shfl_xor(s2, off); }
        float mu = s * (1.f / 64.f);
        float var = s2 * (1.f / 64.f) - mu * mu;
        float rs = rsqrtf(var + EPS);
        #pragma unroll
        for (int j = 0; j < 4; j++) {
            int d = sub * 4 + j;
            hs[row][d] = (hs[row][d] - mu) * rs * g[d] + bb[d];
        }
    }
    __syncthreads();
    int c = t & 63, rg = t >> 6;
    int head = c >> 4, sidx = c & 15;
    float aq[4], ak[4], av[4];
    #pragma unroll
    for (int i = 0; i < 4; i++) { aq[i] = 0.f; ak[i] = 0.f; av[i] = 0.f; }
    for (int kk = 0; kk < 64; kk++) {
        float wq = Wq[(head * 64 + kk) * 16 + sidx];
        float wk = Wk[(head * 64 + kk) * 16 + sidx];
        float wv = Wv[(head * 64 + kk) * 16 + sidx];
        #pragma unroll
        for (int i = 0; i < 4; i++) {
            float h = hs[rg * 4 + i][kk];
            aq[i] += h * wq; ak[i] += h * wk; av[i] += h * wv;
        }
    }
    #pragma unroll
    for (int i = 0; i < 4; i++) {
        int n = r0 + rg * 4 + i;
        int b = n >> 8, tt = n & 255;
        int oidx = ((b * NH + head) * NT + tt) * NHS + sidx;
        q[oidx] = __float2bfloat16(aq[i]);
        k[oidx] = __float2bfloat16(ak[i]);
        v[oidx] = __float2bfloat16(av[i]);
    }
}

// ---------------- MFMA flash attention (unchanged from R11) ----------------
__global__ __launch_bounds__(256) void k_attn(
        const __hip_bfloat16* __restrict__ q, const __hip_bfloat16* __restrict__ k,
        const __hip_bfloat16* __restrict__ v, float* __restrict__ o) {
    __shared__ __bf16 ks[256][24];
    __shared__ __bf16 vt[16][264];
    __shared__ __bf16 ps[4][16][40];

    int blk = blockIdx.x;
    int bh = blk >> 2, tq = blk & 3;
    int t = threadIdx.x;
    int w = t >> 6, l = t & 63;
    int lr = l & 15, lg = l >> 4;
    int nrows = tq * 64 + 64;

    const __hip_bfloat16* kbp = k + (size_t)bh * NT * NHS;
    const __hip_bfloat16* vbp = v + (size_t)bh * NT * NHS;
    for (int r = t; r < nrows; r += 256) {
        const uint4* src = (const uint4*)(kbp + r * 16);
        uint4 k0 = src[0], k1 = src[1];
        *(uint4*)&ks[r][0] = k0;
        *(uint4*)&ks[r][8] = k1;
        const uint4* vsrc = (const uint4*)(vbp + r * 16);
        union { uint4 u[2]; __bf16 h[16]; } vu;
        vu.u[0] = vsrc[0]; vu.u[1] = vsrc[1];
        #pragma unroll
        for (int hh = 0; hh < 16; hh++)
            vt[hh][r] = vu.h[hh];
    }
    __syncthreads();

    bf16x8 zero8;
    #pragma unroll
    for (int e = 0; e < 8; e++) zero8[e] = (__bf16)0.0f;

    int qb = tq * 64 + w * 16;
    bf16x8 qf = zero8;
    if (lg < 2)
        qf = *reinterpret_cast<const bf16x8*>(q + ((size_t)bh * NT + qb + lr) * 16 + lg * 8);

    int ntiles = tq * 4 + w + 1;
    f32x4 oacc = {0.f, 0.f, 0.f, 0.f};
    float lsum[4] = {0.f, 0.f, 0.f, 0.f};

    for (int kt = 0; kt < ntiles; kt++) {
        int kb2 = kt * 16;
        bool diag = (kt == ntiles - 1);

        bf16x8 kf = zero8;
        if (lg < 2)
            kf = *reinterpret_cast<const bf16x8*>(&ks[kb2 + lr][lg * 8]);

        f32x4 s4 = {0.f, 0.f, 0.f, 0.f};
        s4 = __builtin_amdgcn_mfma_f32_16x16x32_bf16(qf, kf, s4, 0, 0, 0);

        #pragma unroll
        for (int reg = 0; reg < 4; reg++) {
            float pv = __expf(s4[reg]);
            if (diag && lr > lg * 4 + reg) pv = 0.f;
            lsum[reg] += pv;
            ps[w][lg * 4 + reg][lr] = (__bf16)pv;
        }

        bf16x8 pf = zero8, vf = zero8;
        if (lg < 2) {
            pf = *reinterpret_cast<const bf16x8*>(&ps[w][lr][lg * 8]);
            vf = *reinterpret_cast<const bf16x8*>(&vt[lr][kb2 + lg * 8]);
        }
        oacc = __builtin_amdgcn_mfma_f32_16x16x32_bf16(pf, vf, oacc, 0, 0, 0);
    }

    #pragma unroll
    for (int reg = 0; reg < 4; reg++) {
        float e = lsum[reg];
        #pragma unroll
        for (int off = 1; off < 16; off <<= 1) e += __shfl_xor(e, off);
        lsum[reg] = e;
    }

    int b = bh >> 2, h = bh & 3;
    #pragma unroll
    for (int reg = 0; reg < 4; reg++) {
        int qrow = qb + lg * 4 + reg;
        o[((size_t)b * NT + qrow) * ND + h * NHS + lr] = oacc[reg] / lsum[reg];
    }
}

// ---------------- proj+res+LN2+MLP1+MLP2+res + next LN1/QKV: 8 rows/block, 512 blocks ----------------
__global__ __launch_bounds__(256) void k_post(
        const float* __restrict__ o, const float* __restrict__ Wo, const float* __restrict__ bo,
        const float* __restrict__ g2, const float* __restrict__ bg2,
        const float* __restrict__ W1, const float* __restrict__ b1,
        const float* __restrict__ W2, const float* __restrict__ b2m,
        float* __restrict__ x,
        const float* __restrict__ g1n, const float* __restrict__ b1n,
        const float* __restrict__ Wqn, const float* __restrict__ Wkn,
        const float* __restrict__ Wvn,
        __hip_bfloat16* __restrict__ q, __hip_bfloat16* __restrict__ k,
        __hip_bfloat16* __restrict__ v,
        const float* __restrict__ lg, const float* __restrict__ lb,
        __hip_bfloat16* __restrict__ xfb, int last) {
    __shared__ float os[8][65];
    __shared__ float xs[8][65];
    __shared__ float as[8][257];
    int t = threadIdx.x;
    int r0 = blockIdx.x * 8;
    for (int i = t; i < 8 * 64; i += 256)
        os[i >> 6][i & 63] = o[r0 * 64 + i];
    __syncthreads();
    int c = t & 63, rg = t >> 6;
    {
        float pr[2] = {0.f, 0.f};
        for (int kk = 0; kk < 64; kk++) {
            float w = Wo[kk * 64 + c];
            #pragma unroll
            for (int i = 0; i < 2; i++) pr[i] += os[rg * 2 + i][kk] * w;
        }
        float bias = bo[c];
        #pragma unroll
        for (int i = 0; i < 2; i++) {
            int row = rg * 2 + i;
            xs[row][c] = x[(r0 + row) * 64 + c] + pr[i] + bias;
        }
    }
    __syncthreads();
    {
        int row = t >> 5, sub = t & 31;
        float s = 0.f, s2 = 0.f;
        #pragma unroll
        for (int j = 0; j < 2; j++) { float vv = xs[row][sub * 2 + j]; s += vv; s2 += vv * vv; }
        #pragma unroll
        for (int off = 1; off < 32; off <<= 1) { s += __shfl_xor(s, off); s2 += __shfl_xor(s2, off); }
        float mu = s * (1.f / 64.f);
        float var = s2 * (1.f / 64.f) - mu * mu;
        float rs = rsqrtf(var + EPS);
        #pragma unroll
        for (int j = 0; j < 2; j++) {
            int d = sub * 2 + j;
            os[row][d] = (xs[row][d] - mu) * rs * g2[d] + bg2[d];
        }
    }
    __syncthreads();
    {
        float m1[8];
        #pragma unroll
        for (int i = 0; i < 8; i++) m1[i] = 0.f;
        for (int kk = 0; kk < 64; kk++) {
            float w = W1[kk * NF + t];
            #pragma unroll
            for (int i = 0; i < 8; i++) m1[i] += os[i][kk] * w;
        }
        float bb1 = b1[t];
        #pragma unroll
        for (int i = 0; i < 8; i++) as[i][t] = fmaxf(m1[i] + bb1, 0.f);
    }
    __syncthreads();
    {
        float m2[2] = {0.f, 0.f};
        for (int kk = 0; kk < 256; kk++) {
            float w = W2[kk * 64 + c];
            #pragma unroll
            for (int i = 0; i < 2; i++) m2[i] += as[rg * 2 + i][kk] * w;
        }
        float bias = b2m[c];
        #pragma unroll
        for (int i = 0; i < 2; i++) {
            int row = rg * 2 + i;
            xs[row][c] += m2[i] + bias;
        }
    }
    __syncthreads();

    if (last) {
        int row = t >> 5, sub = t & 31;
        float s = 0.f, s2 = 0.f;
        #pragma unroll
        for (int j = 0; j < 2; j++) { float vv = xs[row][sub * 2 + j]; s += vv; s2 += vv * vv; }
        #pragma unroll
        for (int off = 1; off < 32; off <<= 1) { s += __shfl_xor(s, off); s2 += __shfl_xor(s2, off); }
        float mu = s * (1.f / 64.f);
        float var = s2 * (1.f / 64.f) - mu * mu;
        float rs = rsqrtf(var + EPS);
        #pragma unroll
        for (int j = 0; j < 2; j++) {
            int d = sub * 2 + j;
            float val = (xs[row][d] - mu) * rs * lg[d] + lb[d];
            xfb[(r0 + row) * 64 + d] = __float2bfloat16(val);
        }
        return;
    }

    {
        #pragma unroll
        for (int i = 0; i < 2; i++) {
            int row = rg * 2 + i;
            x[(r0 + row) * 64 + c] = xs[row][c];
        }
    }
    {
        int row = t >> 5, sub = t & 31;
        float s = 0.f, s2 = 0.f;
        #pragma unroll
        for (int j = 0; j < 2; j++) { float vv = xs[row][sub * 2 + j]; s += vv; s2 += vv * vv; }
        #pragma unroll
        for (int off = 1; off < 32; off <<= 1) { s += __shfl_xor(s, off); s2 += __shfl_xor(s2, off); }
        float mu = s * (1.f / 64.f);
        float var = s2 * (1.f / 64.f) - mu * mu;
        float rs = rsqrtf(var + EPS);
        #pragma unroll
        for (int j = 0; j < 2; j++) {
            int d = sub * 2 + j;
            os[row][d] = (xs[row][d] - mu) * rs * g1n[d] + b1n[d];
        }
    }
    __syncthreads();
    {
        int head = c >> 4, sidx = c & 15;
        float aq[2], ak[2], av[2];
        #pragma unroll
        for (int i = 0; i < 2; i++) { aq[i] = 0.f; ak[i] = 0.f; av[i] = 0.f; }
        for (int kk = 0; kk < 64; kk++) {
            float wq = Wqn[(head * 64 + kk) * 16 + sidx];
            float wk = Wkn[(head * 64 + kk) * 16 + sidx];
            float wv = Wvn[(head * 64 + kk) * 16 + sidx];
            #pragma unroll
            for (int i = 0; i < 2; i++) {
                float h = os[rg * 2 + i][kk];
                aq[i] += h * wq; ak[i] += h * wk; av[i] += h * wv;
            }
        }
        #pragma unroll
        for (int i = 0; i < 2; i++) {
            int n = r0 + rg * 2 + i;
            int b = n >> 8, tt = n & 255;
            int oidx = ((b * NH + head) * NT + tt) * NHS + sidx;
            q[oidx] = __float2bfloat16(aq[i]);
            k[oidx] = __float2bfloat16(ak[i]);
            v[oidx] = __float2bfloat16(av[i]);
        }
    }
}

// ---------------- Whead [64][NV] f32 -> transposed bf16 [NVP][64] ----------------
__global__ __launch_bounds__(256) void k_convW(
        const float* __restrict__ Wh, __hip_bfloat16* __restrict__ whb) {
    __shared__ float w[64][65];
    int t = threadIdx.x;
    int n0 = blockIdx.x * 64;
    for (int i = t; i < 64 * 64; i += 256) {
        int k = i >> 6, c = i & 63;
        int n = n0 + c;
        w[k][c] = (n < NV) ? Wh[k * NV + n] : 0.f;
    }
    __syncthreads();
    int c = t >> 2, kq = t & 3;
    int n = n0 + c;
    union { __hip_bfloat16 h[16]; uint4 u[2]; } pk;
    #pragma unroll
    for (int j = 0; j < 16; j++)
        pk.h[j] = __float2bfloat16(w[kq * 16 + j][c]);
    uint4* dst = (uint4*)(whb + (size_t)n * 64 + kq * 16);
    dst[0] = pk.u[0];
    dst[1] = pk.u[1];
}

// ---------------- head GEMM: register-dieted, serial m-chunks, >=3 waves/SIMD ----------------
// B fragments stay resident (64 VGPR); A/acc/epilogue cycle per 16-row chunk.
// Stores of chunk m drain while chunk m+1 computes.
__global__ __launch_bounds__(256, 3) void k_head(
        const __hip_bfloat16* __restrict__ xfb, const __hip_bfloat16* __restrict__ whb,
        const float* __restrict__ bhead, float* __restrict__ out,
        float* __restrict__ wsum) {
    __shared__ float ssm[4][64];

    int i0 = blockIdx.x;
    int xcd = i0 & 7;
    int j  = i0 >> 3;
    int rb = j / CB_PER_XCD;
    int cb = xcd * CB_PER_XCD + (j - rb * CB_PER_XCD);

    int t = threadIdx.x;
    int w = t >> 6, l = t & 63;
    int lr = l & 15, lg = l >> 4;
    int r0 = rb * 64;
    int cw = cb * 256 + w * 64;
    int c4 = cw + lr * 4;

    // B fragments resident across the whole kernel
    bf16x8 b[4][2];
    {
        const __hip_bfloat16* bp = whb + (size_t)c4 * 64 + lg * 8;
        #pragma unroll
        for (int n = 0; n < 4; n++) {
            b[n][0] = *reinterpret_cast<const bf16x8*>(bp + n * 64);
            b[n][1] = *reinterpret_cast<const bf16x8*>(bp + n * 64 + 32);
        }
    }

    bool all4 = (c4 + 3 < NV);
    float bias[4];
    bool  cok[4];
    if (all4) {
        float4 bv = *(const float4*)(bhead + c4);
        bias[0] = bv.x; bias[1] = bv.y; bias[2] = bv.z; bias[3] = bv.w;
        cok[0] = cok[1] = cok[2] = cok[3] = true;
    } else {
        #pragma unroll
        for (int n = 0; n < 4; n++) {
            int gc = c4 + n;
            cok[n] = (gc < NV);
            bias[n] = cok[n] ? bhead[gc] : 0.f;
        }
    }

    const __hip_bfloat16* ap = xfb + (size_t)(r0 + lr) * 64 + lg * 8;

    #pragma unroll 1
    for (int m = 0; m < 4; m++) {
        bf16x8 a0 = *reinterpret_cast<const bf16x8*>(ap + m * 16 * 64);
        bf16x8 a1 = *reinterpret_cast<const bf16x8*>(ap + m * 16 * 64 + 32);

        f32x4 acc[4];
        #pragma unroll
        for (int n = 0; n < 4; n++)
            #pragma unroll
            for (int j2 = 0; j2 < 4; j2++) acc[n][j2] = 0.f;
        #pragma unroll
        for (int n = 0; n < 4; n++)
            acc[n] = __builtin_amdgcn_mfma_f32_16x16x32_bf16(a0, b[n][0], acc[n], 0, 0, 0);
        #pragma unroll
        for (int n = 0; n < 4; n++)
            acc[n] = __builtin_amdgcn_mfma_f32_16x16x32_bf16(a1, b[n][1], acc[n], 0, 0, 0);

        float es4[4];
        #pragma unroll
        for (int i = 0; i < 4; i++) {
            int rl = 4 * lg + i;
            int grow = r0 + m * 16 + rl;
            float vals[4];
            float e = 0.f;
            #pragma unroll
            for (int n = 0; n < 4; n++) {
                float v = acc[n][i] + bias[n];
                vals[n] = v;
                if (cok[n]) e += __expf(v);
            }
            es4[i] = e;
            float* dst = out + (size_t)grow * NV + c4;
            if (all4) {
                f32x4 vv = {vals[0], vals[1], vals[2], vals[3]};
                __builtin_nontemporal_store(vv, (f32x4*)dst);
            } else {
                #pragma unroll
                for (int n = 0; n < 4; n++)
                    if (cok[n]) __builtin_nontemporal_store(vals[n], dst + n);
            }
        }

        #pragma unroll
        for (int i = 0; i < 4; i++) {
            float e = es4[i];
            #pragma unroll
            for (int off = 1; off < 16; off <<= 1) e += __shfl_xor(e, off);
            if (lr == 0) ssm[w][m * 16 + 4 * lg + i] = e;
        }
    }

    __syncthreads();
    if (t < 64)
        wsum[cb * NN + r0 + t] = ssm[0][t] + ssm[1][t] + ssm[2][t] + ssm[3][t];
}

// ---------------- loss stage 1 ----------------
__global__ void k_loss1(const float* __restrict__ wsum,
                        const float* __restrict__ out, const int* __restrict__ targets,
                        float* __restrict__ lp) {
    int row = blockIdx.x * blockDim.x + threadIdx.x;
    if (row >= NN) return;
    float S = 0.f;
    for (int cb = 0; cb < NCB2; cb++)
        S += wsum[cb * NN + row];
    float lse = logf(S);
    int tg = targets[row];
    float lt = out[(size_t)row * NV + tg];
    lp[row] = lt - lse;
}

// ---------------- loss stage 2 ----------------
__global__ void k_loss2(const float* __restrict__ lp, float* __restrict__ out) {
    __shared__ float red[4];
    int t = threadIdx.x;
    float s = 0.f;
    for (int i = t; i < NN; i += 256) s += lp[i];
    for (int off = 1; off < 64; off <<= 1) s += __shfl_xor(s, off);
    if ((t & 63) == 0) red[t >> 6] = s;
    __syncthreads();
    if (t == 0) {
        float tot = red[0] + red[1] + red[2] + red[3];
        out[LOGITS] = -tot / (float)NN;
    }
}

extern "C" void kernel_launch(void* const* d_in, const int* in_sizes, int n_in,
                              void* d_out, int out_size, void* d_ws, size_t ws_size,
                              hipStream_t stream) {
    const int*   idx     = (const int*)d_in[0];
    const int*   targets = (const int*)d_in[1];
    const float* tok     = (const float*)d_in[2];
    const float* pos     = (const float*)d_in[3];
    const float* Wq      = (const float*)d_in[4];
    const float* Wk      = (const float*)d_in[5];
    const float* Wv      = (const float*)d_in[6];
    const float* Wo      = (const float*)d_in[7];
    const float* bo      = (const float*)d_in[8];
    const float* ln1g    = (const float*)d_in[9];
    const float* ln1b    = (const float*)d_in[10];
    const float* ln2g    = (const float*)d_in[11];
    const float* ln2b    = (const float*)d_in[12];
    const float* W1      = (const float*)d_in[13];
    const float* b1      = (const float*)d_in[14];
    const float* W2      = (const float*)d_in[15];
    const float* b2      = (const float*)d_in[16];
    const float* lnfg    = (const float*)d_in[17];
    const float* lnfb    = (const float*)d_in[18];
    const float* Wh      = (const float*)d_in[19];
    const float* bhead   = (const float*)d_in[20];

    float* ws = (float*)d_ws;
    float* x  = ws + X_OFF;
    __hip_bfloat16* q = (__hip_bfloat16*)(ws + Q_OFF);
    __hip_bfloat16* k = (__hip_bfloat16*)(ws + K_OFF);
    __hip_bfloat16* v = (__hip_bfloat16*)(ws + V_OFF);
    float* o  = ws + O_OFF;
    __hip_bfloat16* xfb = (__hip_bfloat16*)(ws + XFB_OFF);
    float* wsm = ws + WS2_OFF;
    __hip_bfloat16* whb = (__hip_bfloat16*)(ws + WHB_OFF);
    float* lp  = ws + LP_OFF;
    float* out = (float*)d_out;

    k_convW<<<NVP / 64, 256, 0, stream>>>(Wh, whb);

    k_ln_qkv<<<NN / 16, 256, 0, stream>>>(x, ln1g, ln1b, Wq, Wk, Wv, q, k, v,
                                          idx, tok, pos);

    for (int l = 0; l < NL; l++) {
        int last = (l == NL - 1) ? 1 : 0;
        int ln = last ? l : l + 1;
        k_attn<<<NB * NH * 4, 256, 0, stream>>>(q, k, v, o);
        k_post<<<NN / 8, 256, 0, stream>>>(o, Wo + l * ND * ND, bo + l * ND,
                                           ln2g + l * ND, ln2b + l * ND,
                                           W1 + l * ND * NF, b1 + l * NF,
                                           W2 + l * NF * ND, b2 + l * ND, x,
                                           ln1g + ln * ND, ln1b + ln * ND,
                                           Wq + ln * NH * ND * NHS,
                                           Wk + ln * NH * ND * NHS,
                                           Wv + ln * NH * ND * NHS,
                                           q, k, v,
                                           lnfg, lnfb, xfb, last);
    }

    k_head<<<NCB2 * RB_N, 256, 0, stream>>>(xfb, whb, bhead, out, wsm);

    k_loss1<<<NN / 256, 256, 0, stream>>>(wsm, out, targets, lp);
    k_loss2<<<1, 256, 0, stream>>>(lp, out);
}

// Round 14
// 452.996 us; speedup vs baseline: 1.1831x; 1.1831x over previous
//
#include <hip/hip_runtime.h>
#include <hip/hip_bf16.h>
#include <math.h>

// GPT forward: V=50257, B=16, T=256, D=64, H=4, HS=16, L=4, F=256
constexpr int NV  = 50257;
constexpr int NB  = 16;
constexpr int NT  = 256;
constexpr int ND  = 64;
constexpr int NH  = 4;
constexpr int NHS = 16;
constexpr int NL  = 4;
constexpr int NF  = 256;
constexpr int NN  = NB * NT;        // 4096 rows
constexpr float EPS = 1e-5f;

constexpr int NCB2 = 200;                    // head col blocks of 256 (8-divisible)
constexpr int NVP  = NCB2 * 256;             // 51200 padded vocab
constexpr int LOGITS = NN * NV;              // 205,852,672
constexpr int RB_N  = NN / 64;               // 64 row blocks
constexpr int CB_PER_XCD = NCB2 / 8;         // 25

// workspace layout (float offsets)
constexpr int X_OFF   = 0;                        // [NN*ND] f32
constexpr int Q_OFF   = X_OFF  + NN * ND;         // bf16 [B,H,T,HS]
constexpr int K_OFF   = Q_OFF  + NN * ND;
constexpr int V_OFF   = K_OFF  + NN * ND;
constexpr int O_OFF   = V_OFF  + NN * ND;         // f32 [NN][64]
constexpr int A_OFF   = O_OFF  + NN * ND;         // (spacer)
constexpr int XFB_OFF = A_OFF  + NN * NF;         // bf16 [NN*ND]
constexpr int WM_OFF  = XFB_OFF + NN * ND / 2;    // (spacer)
constexpr int WS2_OFF = WM_OFF + 200 * NN;        // [NCB2*NN] sum-exp partials
constexpr int WHB_OFF = WS2_OFF + 200 * NN;       // bf16 [NVP*64]
constexpr int LP_OFF  = WHB_OFF + NVP * 32;       // [NN]

typedef __bf16 bf16x8 __attribute__((ext_vector_type(8)));
typedef float  f32x4  __attribute__((ext_vector_type(4)));

// ---------------- embed + LN1 + QKV (layer 0 only; 16 rows/block, 256 blocks) ----------------
__global__ __launch_bounds__(256) void k_ln_qkv(
        float* __restrict__ x, const float* __restrict__ g, const float* __restrict__ bb,
        const float* __restrict__ Wq, const float* __restrict__ Wk, const float* __restrict__ Wv,
        __hip_bfloat16* __restrict__ q, __hip_bfloat16* __restrict__ k,
        __hip_bfloat16* __restrict__ v,
        const int* __restrict__ idx, const float* __restrict__ tok,
        const float* __restrict__ pos) {
    __shared__ float hs[16][65];
    int t = threadIdx.x;
    int r0 = blockIdx.x * 16;
    for (int i = t; i < 16 * 64; i += 256) {
        int n = r0 + (i >> 6);
        int tt = n & (NT - 1), d = i & 63;
        float e = tok[idx[n] * ND + d] + pos[tt * ND + d];
        hs[i >> 6][i & 63] = e;
        x[(size_t)r0 * 64 + i] = e;
    }
    __syncthreads();
    {
        int row = t >> 4, sub = t & 15;
        float s = 0.f, s2 = 0.f;
        #pragma unroll
        for (int j = 0; j < 4; j++) { float vv = hs[row][sub * 4 + j]; s += vv; s2 += vv * vv; }
        #pragma unroll
        for (int off = 1; off < 16; off <<= 1) { s += __shfl_xor(s, off); s2 += __shfl_xor(s2, off); }
        float mu = s * (1.f / 64.f);
        float var = s2 * (1.f / 64.f) - mu * mu;
        float rs = rsqrtf(var + EPS);
        #pragma unroll
        for (int j = 0; j < 4; j++) {
            int d = sub * 4 + j;
            hs[row][d] = (hs[row][d] - mu) * rs * g[d] + bb[d];
        }
    }
    __syncthreads();
    int c = t & 63, rg = t >> 6;
    int head = c >> 4, sidx = c & 15;
    float aq[4], ak[4], av[4];
    #pragma unroll
    for (int i = 0; i < 4; i++) { aq[i] = 0.f; ak[i] = 0.f; av[i] = 0.f; }
    for (int kk = 0; kk < 64; kk++) {
        float wq = Wq[(head * 64 + kk) * 16 + sidx];
        float wk = Wk[(head * 64 + kk) * 16 + sidx];
        float wv = Wv[(head * 64 + kk) * 16 + sidx];
        #pragma unroll
        for (int i = 0; i < 4; i++) {
            float h = hs[rg * 4 + i][kk];
            aq[i] += h * wq; ak[i] += h * wk; av[i] += h * wv;
        }
    }
    #pragma unroll
    for (int i = 0; i < 4; i++) {
        int n = r0 + rg * 4 + i;
        int b = n >> 8, tt = n & 255;
        int oidx = ((b * NH + head) * NT + tt) * NHS + sidx;
        q[oidx] = __float2bfloat16(aq[i]);
        k[oidx] = __float2bfloat16(ak[i]);
        v[oidx] = __float2bfloat16(av[i]);
    }
}

// ---------------- MFMA flash attention (unchanged from R11) ----------------
__global__ __launch_bounds__(256) void k_attn(
        const __hip_bfloat16* __restrict__ q, const __hip_bfloat16* __restrict__ k,
        const __hip_bfloat16* __restrict__ v, float* __restrict__ o) {
    __shared__ __bf16 ks[256][24];
    __shared__ __bf16 vt[16][264];
    __shared__ __bf16 ps[4][16][40];

    int blk = blockIdx.x;
    int bh = blk >> 2, tq = blk & 3;
    int t = threadIdx.x;
    int w = t >> 6, l = t & 63;
    int lr = l & 15, lg = l >> 4;
    int nrows = tq * 64 + 64;

    const __hip_bfloat16* kbp = k + (size_t)bh * NT * NHS;
    const __hip_bfloat16* vbp = v + (size_t)bh * NT * NHS;
    for (int r = t; r < nrows; r += 256) {
        const uint4* src = (const uint4*)(kbp + r * 16);
        uint4 k0 = src[0], k1 = src[1];
        *(uint4*)&ks[r][0] = k0;
        *(uint4*)&ks[r][8] = k1;
        const uint4* vsrc = (const uint4*)(vbp + r * 16);
        union { uint4 u[2]; __bf16 h[16]; } vu;
        vu.u[0] = vsrc[0]; vu.u[1] = vsrc[1];
        #pragma unroll
        for (int hh = 0; hh < 16; hh++)
            vt[hh][r] = vu.h[hh];
    }
    __syncthreads();

    bf16x8 zero8;
    #pragma unroll
    for (int e = 0; e < 8; e++) zero8[e] = (__bf16)0.0f;

    int qb = tq * 64 + w * 16;
    bf16x8 qf = zero8;
    if (lg < 2)
        qf = *reinterpret_cast<const bf16x8*>(q + ((size_t)bh * NT + qb + lr) * 16 + lg * 8);

    int ntiles = tq * 4 + w + 1;
    f32x4 oacc = {0.f, 0.f, 0.f, 0.f};
    float lsum[4] = {0.f, 0.f, 0.f, 0.f};

    for (int kt = 0; kt < ntiles; kt++) {
        int kb2 = kt * 16;
        bool diag = (kt == ntiles - 1);

        bf16x8 kf = zero8;
        if (lg < 2)
            kf = *reinterpret_cast<const bf16x8*>(&ks[kb2 + lr][lg * 8]);

        f32x4 s4 = {0.f, 0.f, 0.f, 0.f};
        s4 = __builtin_amdgcn_mfma_f32_16x16x32_bf16(qf, kf, s4, 0, 0, 0);

        #pragma unroll
        for (int reg = 0; reg < 4; reg++) {
            float pv = __expf(s4[reg]);
            if (diag && lr > lg * 4 + reg) pv = 0.f;
            lsum[reg] += pv;
            ps[w][lg * 4 + reg][lr] = (__bf16)pv;
        }

        bf16x8 pf = zero8, vf = zero8;
        if (lg < 2) {
            pf = *reinterpret_cast<const bf16x8*>(&ps[w][lr][lg * 8]);
            vf = *reinterpret_cast<const bf16x8*>(&vt[lr][kb2 + lg * 8]);
        }
        oacc = __builtin_amdgcn_mfma_f32_16x16x32_bf16(pf, vf, oacc, 0, 0, 0);
    }

    #pragma unroll
    for (int reg = 0; reg < 4; reg++) {
        float e = lsum[reg];
        #pragma unroll
        for (int off = 1; off < 16; off <<= 1) e += __shfl_xor(e, off);
        lsum[reg] = e;
    }

    int b = bh >> 2, h = bh & 3;
    #pragma unroll
    for (int reg = 0; reg < 4; reg++) {
        int qrow = qb + lg * 4 + reg;
        o[((size_t)b * NT + qrow) * ND + h * NHS + lr] = oacc[reg] / lsum[reg];
    }
}

// ---------------- proj+res+LN2+MLP1+MLP2+res + next LN1/QKV: 8 rows/block, 512 blocks ----------------
__global__ __launch_bounds__(256) void k_post(
        const float* __restrict__ o, const float* __restrict__ Wo, const float* __restrict__ bo,
        const float* __restrict__ g2, const float* __restrict__ bg2,
        const float* __restrict__ W1, const float* __restrict__ b1,
        const float* __restrict__ W2, const float* __restrict__ b2m,
        float* __restrict__ x,
        const float* __restrict__ g1n, const float* __restrict__ b1n,
        const float* __restrict__ Wqn, const float* __restrict__ Wkn,
        const float* __restrict__ Wvn,
        __hip_bfloat16* __restrict__ q, __hip_bfloat16* __restrict__ k,
        __hip_bfloat16* __restrict__ v,
        const float* __restrict__ lg, const float* __restrict__ lb,
        __hip_bfloat16* __restrict__ xfb, int last) {
    __shared__ float os[8][65];
    __shared__ float xs[8][65];
    __shared__ float as[8][257];
    int t = threadIdx.x;
    int r0 = blockIdx.x * 8;
    for (int i = t; i < 8 * 64; i += 256)
        os[i >> 6][i & 63] = o[r0 * 64 + i];
    __syncthreads();
    int c = t & 63, rg = t >> 6;
    {
        float pr[2] = {0.f, 0.f};
        for (int kk = 0; kk < 64; kk++) {
            float w = Wo[kk * 64 + c];
            #pragma unroll
            for (int i = 0; i < 2; i++) pr[i] += os[rg * 2 + i][kk] * w;
        }
        float bias = bo[c];
        #pragma unroll
        for (int i = 0; i < 2; i++) {
            int row = rg * 2 + i;
            xs[row][c] = x[(r0 + row) * 64 + c] + pr[i] + bias;
        }
    }
    __syncthreads();
    {
        int row = t >> 5, sub = t & 31;
        float s = 0.f, s2 = 0.f;
        #pragma unroll
        for (int j = 0; j < 2; j++) { float vv = xs[row][sub * 2 + j]; s += vv; s2 += vv * vv; }
        #pragma unroll
        for (int off = 1; off < 32; off <<= 1) { s += __shfl_xor(s, off); s2 += __shfl_xor(s2, off); }
        float mu = s * (1.f / 64.f);
        float var = s2 * (1.f / 64.f) - mu * mu;
        float rs = rsqrtf(var + EPS);
        #pragma unroll
        for (int j = 0; j < 2; j++) {
            int d = sub * 2 + j;
            os[row][d] = (xs[row][d] - mu) * rs * g2[d] + bg2[d];
        }
    }
    __syncthreads();
    {
        float m1[8];
        #pragma unroll
        for (int i = 0; i < 8; i++) m1[i] = 0.f;
        for (int kk = 0; kk < 64; kk++) {
            float w = W1[kk * NF + t];
            #pragma unroll
            for (int i = 0; i < 8; i++) m1[i] += os[i][kk] * w;
        }
        float bb1 = b1[t];
        #pragma unroll
        for (int i = 0; i < 8; i++) as[i][t] = fmaxf(m1[i] + bb1, 0.f);
    }
    __syncthreads();
    {
        float m2[2] = {0.f, 0.f};
        for (int kk = 0; kk < 256; kk++) {
            float w = W2[kk * 64 + c];
            #pragma unroll
            for (int i = 0; i < 2; i++) m2[i] += as[rg * 2 + i][kk] * w;
        }
        float bias = b2m[c];
        #pragma unroll
        for (int i = 0; i < 2; i++) {
            int row = rg * 2 + i;
            xs[row][c] += m2[i] + bias;
        }
    }
    __syncthreads();

    if (last) {
        int row = t >> 5, sub = t & 31;
        float s = 0.f, s2 = 0.f;
        #pragma unroll
        for (int j = 0; j < 2; j++) { float vv = xs[row][sub * 2 + j]; s += vv; s2 += vv * vv; }
        #pragma unroll
        for (int off = 1; off < 32; off <<= 1) { s += __shfl_xor(s, off); s2 += __shfl_xor(s2, off); }
        float mu = s * (1.f / 64.f);
        float var = s2 * (1.f / 64.f) - mu * mu;
        float rs = rsqrtf(var + EPS);
        #pragma unroll
        for (int j = 0; j < 2; j++) {
            int d = sub * 2 + j;
            float val = (xs[row][d] - mu) * rs * lg[d] + lb[d];
            xfb[(r0 + row) * 64 + d] = __float2bfloat16(val);
        }
        return;
    }

    {
        #pragma unroll
        for (int i = 0; i < 2; i++) {
            int row = rg * 2 + i;
            x[(r0 + row) * 64 + c] = xs[row][c];
        }
    }
    {
        int row = t >> 5, sub = t & 31;
        float s = 0.f, s2 = 0.f;
        #pragma unroll
        for (int j = 0; j < 2; j++) { float vv = xs[row][sub * 2 + j]; s += vv; s2 += vv * vv; }
        #pragma unroll
        for (int off = 1; off < 32; off <<= 1) { s += __shfl_xor(s, off); s2 += __shfl_xor(s2, off); }
        float mu = s * (1.f / 64.f);
        float var = s2 * (1.f / 64.f) - mu * mu;
        float rs = rsqrtf(var + EPS);
        #pragma unroll
        for (int j = 0; j < 2; j++) {
            int d = sub * 2 + j;
            os[row][d] = (xs[row][d] - mu) * rs * g1n[d] + b1n[d];
        }
    }
    __syncthreads();
    {
        int head = c >> 4, sidx = c & 15;
        float aq[2], ak[2], av[2];
        #pragma unroll
        for (int i = 0; i < 2; i++) { aq[i] = 0.f; ak[i] = 0.f; av[i] = 0.f; }
        for (int kk = 0; kk < 64; kk++) {
            float wq = Wqn[(head * 64 + kk) * 16 + sidx];
            float wk = Wkn[(head * 64 + kk) * 16 + sidx];
            float wv = Wvn[(head * 64 + kk) * 16 + sidx];
            #pragma unroll
            for (int i = 0; i < 2; i++) {
                float h = os[rg * 2 + i][kk];
                aq[i] += h * wq; ak[i] += h * wk; av[i] += h * wv;
            }
        }
        #pragma unroll
        for (int i = 0; i < 2; i++) {
            int n = r0 + rg * 2 + i;
            int b = n >> 8, tt = n & 255;
            int oidx = ((b * NH + head) * NT + tt) * NHS + sidx;
            q[oidx] = __float2bfloat16(aq[i]);
            k[oidx] = __float2bfloat16(ak[i]);
            v[oidx] = __float2bfloat16(av[i]);
        }
    }
}

// ---------------- Whead [64][NV] f32 -> transposed bf16 [NVP][64] ----------------
__global__ __launch_bounds__(256) void k_convW(
        const float* __restrict__ Wh, __hip_bfloat16* __restrict__ whb) {
    __shared__ float w[64][65];
    int t = threadIdx.x;
    int n0 = blockIdx.x * 64;
    for (int i = t; i < 64 * 64; i += 256) {
        int k = i >> 6, c = i & 63;
        int n = n0 + c;
        w[k][c] = (n < NV) ? Wh[k * NV + n] : 0.f;
    }
    __syncthreads();
    int c = t >> 2, kq = t & 3;
    int n = n0 + c;
    union { __hip_bfloat16 h[16]; uint4 u[2]; } pk;
    #pragma unroll
    for (int j = 0; j < 16; j++)
        pk.h[j] = __float2bfloat16(w[kq * 16 + j][c]);
    uint4* dst = (uint4*)(whb + (size_t)n * 64 + kq * 16);
    dst[0] = pk.u[0];
    dst[1] = pk.u[1];
}

// ---------------- head GEMM (bf16 MFMA) + bias + fused row sum-exp ----------------
// R12 structure; PLAIN stores (L2 write-combining merges the misaligned
// partial lines that NV=50257's odd row stride creates — nt-stores forfeit it).
__global__ __launch_bounds__(256) void k_head(
        const __hip_bfloat16* __restrict__ xfb, const __hip_bfloat16* __restrict__ whb,
        const float* __restrict__ bhead, float* __restrict__ out,
        float* __restrict__ wsum) {
    __shared__ float ssm[4][64];

    int i0 = blockIdx.x;
    int xcd = i0 & 7;
    int j  = i0 >> 3;
    int rb = j / CB_PER_XCD;
    int cb = xcd * CB_PER_XCD + (j - rb * CB_PER_XCD);

    int t = threadIdx.x;
    int w = t >> 6, l = t & 63;
    int lr = l & 15, lg = l >> 4;
    int r0 = rb * 64;
    int cw = cb * 256 + w * 64;
    int c4 = cw + lr * 4;

    bf16x8 a[4][2], b[4][2];
    {
        const __hip_bfloat16* ap = xfb + (size_t)(r0 + lr) * 64 + lg * 8;
        #pragma unroll
        for (int m = 0; m < 4; m++)
            #pragma unroll
            for (int ks = 0; ks < 2; ks++)
                a[m][ks] = *reinterpret_cast<const bf16x8*>(ap + m * 16 * 64 + ks * 32);
        const __hip_bfloat16* bp = whb + (size_t)c4 * 64 + lg * 8;
        #pragma unroll
        for (int n = 0; n < 4; n++)
            #pragma unroll
            for (int ks = 0; ks < 2; ks++)
                b[n][ks] = *reinterpret_cast<const bf16x8*>(bp + n * 64 + ks * 32);
    }

    f32x4 acc[4][4];
    #pragma unroll
    for (int m = 0; m < 4; m++)
        #pragma unroll
        for (int n = 0; n < 4; n++)
            #pragma unroll
            for (int j2 = 0; j2 < 4; j2++) acc[m][n][j2] = 0.f;

    #pragma unroll
    for (int ks = 0; ks < 2; ks++)
        #pragma unroll
        for (int m = 0; m < 4; m++)
            #pragma unroll
            for (int n = 0; n < 4; n++)
                acc[m][n] = __builtin_amdgcn_mfma_f32_16x16x32_bf16(a[m][ks], b[n][ks], acc[m][n], 0, 0, 0);

    bool all4 = (c4 + 3 < NV);
    float bias[4];
    bool  cok[4];
    if (all4) {
        float4 bv = *(const float4*)(bhead + c4);
        bias[0] = bv.x; bias[1] = bv.y; bias[2] = bv.z; bias[3] = bv.w;
        cok[0] = cok[1] = cok[2] = cok[3] = true;
    } else {
        #pragma unroll
        for (int n = 0; n < 4; n++) {
            int gc = c4 + n;
            cok[n] = (gc < NV);
            bias[n] = cok[n] ? bhead[gc] : 0.f;
        }
    }

    float es[16];
    #pragma unroll
    for (int m = 0; m < 4; m++) {
        #pragma unroll
        for (int i = 0; i < 4; i++) {
            int rl = 4 * lg + i;
            int grow = r0 + m * 16 + rl;
            float vals[4];
            float e = 0.f;
            #pragma unroll
            for (int n = 0; n < 4; n++) {
                float v = acc[m][n][i] + bias[n];
                vals[n] = v;
                if (cok[n]) e += __expf(v);
            }
            es[m * 4 + i] = e;
            float* dst = out + (size_t)grow * NV + c4;
            if (all4) {
                f32x4 vv = {vals[0], vals[1], vals[2], vals[3]};
                *(f32x4*)dst = vv;
            } else {
                #pragma unroll
                for (int n = 0; n < 4; n++)
                    if (cok[n]) dst[n] = vals[n];
            }
        }
    }

    #pragma unroll
    for (int m = 0; m < 4; m++) {
        #pragma unroll
        for (int i = 0; i < 4; i++) {
            float e = es[m * 4 + i];
            #pragma unroll
            for (int off = 1; off < 16; off <<= 1) e += __shfl_xor(e, off);
            if (lr == 0) ssm[w][m * 16 + 4 * lg + i] = e;
        }
    }

    __syncthreads();
    if (t < 64)
        wsum[cb * NN + r0 + t] = ssm[0][t] + ssm[1][t] + ssm[2][t] + ssm[3][t];
}

// ---------------- loss stage 1 ----------------
__global__ void k_loss1(const float* __restrict__ wsum,
                        const float* __restrict__ out, const int* __restrict__ targets,
                        float* __restrict__ lp) {
    int row = blockIdx.x * blockDim.x + threadIdx.x;
    if (row >= NN) return;
    float S = 0.f;
    for (int cb = 0; cb < NCB2; cb++)
        S += wsum[cb * NN + row];
    float lse = logf(S);
    int tg = targets[row];
    float lt = out[(size_t)row * NV + tg];
    lp[row] = lt - lse;
}

// ---------------- loss stage 2 ----------------
__global__ void k_loss2(const float* __restrict__ lp, float* __restrict__ out) {
    __shared__ float red[4];
    int t = threadIdx.x;
    float s = 0.f;
    for (int i = t; i < NN; i += 256) s += lp[i];
    for (int off = 1; off < 64; off <<= 1) s += __shfl_xor(s, off);
    if ((t & 63) == 0) red[t >> 6] = s;
    __syncthreads();
    if (t == 0) {
        float tot = red[0] + red[1] + red[2] + red[3];
        out[LOGITS] = -tot / (float)NN;
    }
}

extern "C" void kernel_launch(void* const* d_in, const int* in_sizes, int n_in,
                              void* d_out, int out_size, void* d_ws, size_t ws_size,
                              hipStream_t stream) {
    const int*   idx     = (const int*)d_in[0];
    const int*   targets = (const int*)d_in[1];
    const float* tok     = (const float*)d_in[2];
    const float* pos     = (const float*)d_in[3];
    const float* Wq      = (const float*)d_in[4];
    const float* Wk      = (const float*)d_in[5];
    const float* Wv      = (const float*)d_in[6];
    const float* Wo      = (const float*)d_in[7];
    const float* bo      = (const float*)d_in[8];
    const float* ln1g    = (const float*)d_in[9];
    const float* ln1b    = (const float*)d_in[10];
    const float* ln2g    = (const float*)d_in[11];
    const float* ln2b    = (const float*)d_in[12];
    const float* W1      = (const float*)d_in[13];
    const float* b1      = (const float*)d_in[14];
    const float* W2      = (const float*)d_in[15];
    const float* b2      = (const float*)d_in[16];
    const float* lnfg    = (const float*)d_in[17];
    const float* lnfb    = (const float*)d_in[18];
    const float* Wh      = (const float*)d_in[19];
    const float* bhead   = (const float*)d_in[20];

    float* ws = (float*)d_ws;
    float* x  = ws + X_OFF;
    __hip_bfloat16* q = (__hip_bfloat16*)(ws + Q_OFF);
    __hip_bfloat16* k = (__hip_bfloat16*)(ws + K_OFF);
    __hip_bfloat16* v = (__hip_bfloat16*)(ws + V_OFF);
    float* o  = ws + O_OFF;
    __hip_bfloat16* xfb = (__hip_bfloat16*)(ws + XFB_OFF);
    float* wsm = ws + WS2_OFF;
    __hip_bfloat16* whb = (__hip_bfloat16*)(ws + WHB_OFF);
    float* lp  = ws + LP_OFF;
    float* out = (float*)d_out;

    k_convW<<<NVP / 64, 256, 0, stream>>>(Wh, whb);

    k_ln_qkv<<<NN / 16, 256, 0, stream>>>(x, ln1g, ln1b, Wq, Wk, Wv, q, k, v,
                                          idx, tok, pos);

    for (int l = 0; l < NL; l++) {
        int last = (l == NL - 1) ? 1 : 0;
        int ln = last ? l : l + 1;
        k_attn<<<NB * NH * 4, 256, 0, stream>>>(q, k, v, o);
        k_post<<<NN / 8, 256, 0, stream>>>(o, Wo + l * ND * ND, bo + l * ND,
                                           ln2g + l * ND, ln2b + l * ND,
                                           W1 + l * ND * NF, b1 + l * NF,
                                           W2 + l * NF * ND, b2 + l * ND, x,
                                           ln1g + ln * ND, ln1b + ln * ND,
                                           Wq + ln * NH * ND * NHS,
                                           Wk + ln * NH * ND * NHS,
                                           Wv + ln * NH * ND * NHS,
                                           q, k, v,
                                           lnfg, lnfb, xfb, last);
    }

    k_head<<<NCB2 * RB_N, 256, 0, stream>>>(xfb, whb, bhead, out, wsm);

    k_loss1<<<NN / 256, 256, 0, stream>>>(wsm, out, targets, lp);
    k_loss2<<<1, 256, 0, stream>>>(lp, out);
}

// Round 15
// 423.819 us; speedup vs baseline: 1.2646x; 1.0688x over previous
//
#include <hip/hip_runtime.h>
#include <hip/hip_bf16.h>
#include <math.h>

// GPT forward: V=50257, B=16, T=256, D=64, H=4, HS=16, L=4, F=256
constexpr int NV  = 50257;
constexpr int NB  = 16;
constexpr int NT  = 256;
constexpr int ND  = 64;
constexpr int NH  = 4;
constexpr int NHS = 16;
constexpr int NL  = 4;
constexpr int NF  = 256;
constexpr int NN  = NB * NT;        // 4096 rows
constexpr float EPS = 1e-5f;

constexpr int NCB2 = 200;                    // head col blocks of 256 (8-divisible)
constexpr int NVP  = NCB2 * 256;             // 51200 padded vocab
constexpr int LOGITS = NN * NV;              // 205,852,672
constexpr int RB_N  = NN / 64;               // 64 row blocks
constexpr int CB_PER_XCD = NCB2 / 8;         // 25

// workspace layout (float offsets)
constexpr int X_OFF   = 0;                        // [NN*ND] f32
constexpr int Q_OFF   = X_OFF  + NN * ND;         // bf16 [B,H,T,HS]
constexpr int K_OFF   = Q_OFF  + NN * ND;
constexpr int V_OFF   = K_OFF  + NN * ND;
constexpr int O_OFF   = V_OFF  + NN * ND;         // f32 [NN][64]
constexpr int A_OFF   = O_OFF  + NN * ND;         // (spacer)
constexpr int XFB_OFF = A_OFF  + NN * NF;         // bf16 [NN*ND]
constexpr int WM_OFF  = XFB_OFF + NN * ND / 2;    // (spacer)
constexpr int WS2_OFF = WM_OFF + 200 * NN;        // [NCB2*NN] sum-exp partials
constexpr int WHB_OFF = WS2_OFF + 200 * NN;       // bf16 [NVP*64]
constexpr int LP_OFF  = WHB_OFF + NVP * 32;       // [NN]

typedef __bf16 bf16x8 __attribute__((ext_vector_type(8)));
typedef float  f32x4  __attribute__((ext_vector_type(4)));

// ---------------- embed + LN1 + QKV (layer 0 only; 16 rows/block, 256 blocks) ----------------
__global__ __launch_bounds__(256) void k_ln_qkv(
        float* __restrict__ x, const float* __restrict__ g, const float* __restrict__ bb,
        const float* __restrict__ Wq, const float* __restrict__ Wk, const float* __restrict__ Wv,
        __hip_bfloat16* __restrict__ q, __hip_bfloat16* __restrict__ k,
        __hip_bfloat16* __restrict__ v,
        const int* __restrict__ idx, const float* __restrict__ tok,
        const float* __restrict__ pos) {
    __shared__ float hs[16][65];
    int t = threadIdx.x;
    int r0 = blockIdx.x * 16;
    for (int i = t; i < 16 * 64; i += 256) {
        int n = r0 + (i >> 6);
        int tt = n & (NT - 1), d = i & 63;
        float e = tok[idx[n] * ND + d] + pos[tt * ND + d];
        hs[i >> 6][i & 63] = e;
        x[(size_t)r0 * 64 + i] = e;
    }
    __syncthreads();
    {
        int row = t >> 4, sub = t & 15;
        float s = 0.f, s2 = 0.f;
        #pragma unroll
        for (int j = 0; j < 4; j++) { float vv = hs[row][sub * 4 + j]; s += vv; s2 += vv * vv; }
        #pragma unroll
        for (int off = 1; off < 16; off <<= 1) { s += __shfl_xor(s, off); s2 += __shfl_xor(s2, off); }
        float mu = s * (1.f / 64.f);
        float var = s2 * (1.f / 64.f) - mu * mu;
        float rs = rsqrtf(var + EPS);
        #pragma unroll
        for (int j = 0; j < 4; j++) {
            int d = sub * 4 + j;
            hs[row][d] = (hs[row][d] - mu) * rs * g[d] + bb[d];
        }
    }
    __syncthreads();
    int c = t & 63, rg = t >> 6;
    int head = c >> 4, sidx = c & 15;
    float aq[4], ak[4], av[4];
    #pragma unroll
    for (int i = 0; i < 4; i++) { aq[i] = 0.f; ak[i] = 0.f; av[i] = 0.f; }
    for (int kk = 0; kk < 64; kk++) {
        float wq = Wq[(head * 64 + kk) * 16 + sidx];
        float wk = Wk[(head * 64 + kk) * 16 + sidx];
        float wv = Wv[(head * 64 + kk) * 16 + sidx];
        #pragma unroll
        for (int i = 0; i < 4; i++) {
            float h = hs[rg * 4 + i][kk];
            aq[i] += h * wq; ak[i] += h * wk; av[i] += h * wv;
        }
    }
    #pragma unroll
    for (int i = 0; i < 4; i++) {
        int n = r0 + rg * 4 + i;
        int b = n >> 8, tt = n & 255;
        int oidx = ((b * NH + head) * NT + tt) * NHS + sidx;
        q[oidx] = __float2bfloat16(aq[i]);
        k[oidx] = __float2bfloat16(ak[i]);
        v[oidx] = __float2bfloat16(av[i]);
    }
}

// ---------------- MFMA flash attention (unchanged) ----------------
__global__ __launch_bounds__(256) void k_attn(
        const __hip_bfloat16* __restrict__ q, const __hip_bfloat16* __restrict__ k,
        const __hip_bfloat16* __restrict__ v, float* __restrict__ o) {
    __shared__ __bf16 ks[256][24];
    __shared__ __bf16 vt[16][264];
    __shared__ __bf16 ps[4][16][40];

    int blk = blockIdx.x;
    int bh = blk >> 2, tq = blk & 3;
    int t = threadIdx.x;
    int w = t >> 6, l = t & 63;
    int lr = l & 15, lg = l >> 4;
    int nrows = tq * 64 + 64;

    const __hip_bfloat16* kbp = k + (size_t)bh * NT * NHS;
    const __hip_bfloat16* vbp = v + (size_t)bh * NT * NHS;
    for (int r = t; r < nrows; r += 256) {
        const uint4* src = (const uint4*)(kbp + r * 16);
        uint4 k0 = src[0], k1 = src[1];
        *(uint4*)&ks[r][0] = k0;
        *(uint4*)&ks[r][8] = k1;
        const uint4* vsrc = (const uint4*)(vbp + r * 16);
        union { uint4 u[2]; __bf16 h[16]; } vu;
        vu.u[0] = vsrc[0]; vu.u[1] = vsrc[1];
        #pragma unroll
        for (int hh = 0; hh < 16; hh++)
            vt[hh][r] = vu.h[hh];
    }
    __syncthreads();

    bf16x8 zero8;
    #pragma unroll
    for (int e = 0; e < 8; e++) zero8[e] = (__bf16)0.0f;

    int qb = tq * 64 + w * 16;
    bf16x8 qf = zero8;
    if (lg < 2)
        qf = *reinterpret_cast<const bf16x8*>(q + ((size_t)bh * NT + qb + lr) * 16 + lg * 8);

    int ntiles = tq * 4 + w + 1;
    f32x4 oacc = {0.f, 0.f, 0.f, 0.f};
    float lsum[4] = {0.f, 0.f, 0.f, 0.f};

    for (int kt = 0; kt < ntiles; kt++) {
        int kb2 = kt * 16;
        bool diag = (kt == ntiles - 1);

        bf16x8 kf = zero8;
        if (lg < 2)
            kf = *reinterpret_cast<const bf16x8*>(&ks[kb2 + lr][lg * 8]);

        f32x4 s4 = {0.f, 0.f, 0.f, 0.f};
        s4 = __builtin_amdgcn_mfma_f32_16x16x32_bf16(qf, kf, s4, 0, 0, 0);

        #pragma unroll
        for (int reg = 0; reg < 4; reg++) {
            float pv = __expf(s4[reg]);
            if (diag && lr > lg * 4 + reg) pv = 0.f;
            lsum[reg] += pv;
            ps[w][lg * 4 + reg][lr] = (__bf16)pv;
        }

        bf16x8 pf = zero8, vf = zero8;
        if (lg < 2) {
            pf = *reinterpret_cast<const bf16x8*>(&ps[w][lr][lg * 8]);
            vf = *reinterpret_cast<const bf16x8*>(&vt[lr][kb2 + lg * 8]);
        }
        oacc = __builtin_amdgcn_mfma_f32_16x16x32_bf16(pf, vf, oacc, 0, 0, 0);
    }

    #pragma unroll
    for (int reg = 0; reg < 4; reg++) {
        float e = lsum[reg];
        #pragma unroll
        for (int off = 1; off < 16; off <<= 1) e += __shfl_xor(e, off);
        lsum[reg] = e;
    }

    int b = bh >> 2, h = bh & 3;
    #pragma unroll
    for (int reg = 0; reg < 4; reg++) {
        int qrow = qb + lg * 4 + reg;
        o[((size_t)b * NT + qrow) * ND + h * NHS + lr] = oacc[reg] / lsum[reg];
    }
}

// ---------------- proj+res+LN2+MLP1+MLP2+res + next LN1/QKV: 8 rows/block (unchanged) ----------------
__global__ __launch_bounds__(256) void k_post(
        const float* __restrict__ o, const float* __restrict__ Wo, const float* __restrict__ bo,
        const float* __restrict__ g2, const float* __restrict__ bg2,
        const float* __restrict__ W1, const float* __restrict__ b1,
        const float* __restrict__ W2, const float* __restrict__ b2m,
        float* __restrict__ x,
        const float* __restrict__ g1n, const float* __restrict__ b1n,
        const float* __restrict__ Wqn, const float* __restrict__ Wkn,
        const float* __restrict__ Wvn,
        __hip_bfloat16* __restrict__ q, __hip_bfloat16* __restrict__ k,
        __hip_bfloat16* __restrict__ v,
        const float* __restrict__ lg, const float* __restrict__ lb,
        __hip_bfloat16* __restrict__ xfb, int last) {
    __shared__ float os[8][65];
    __shared__ float xs[8][65];
    __shared__ float as[8][257];
    int t = threadIdx.x;
    int r0 = blockIdx.x * 8;
    for (int i = t; i < 8 * 64; i += 256)
        os[i >> 6][i & 63] = o[r0 * 64 + i];
    __syncthreads();
    int c = t & 63, rg = t >> 6;
    {
        float pr[2] = {0.f, 0.f};
        for (int kk = 0; kk < 64; kk++) {
            float w = Wo[kk * 64 + c];
            #pragma unroll
            for (int i = 0; i < 2; i++) pr[i] += os[rg * 2 + i][kk] * w;
        }
        float bias = bo[c];
        #pragma unroll
        for (int i = 0; i < 2; i++) {
            int row = rg * 2 + i;
            xs[row][c] = x[(r0 + row) * 64 + c] + pr[i] + bias;
        }
    }
    __syncthreads();
    {
        int row = t >> 5, sub = t & 31;
        float s = 0.f, s2 = 0.f;
        #pragma unroll
        for (int j = 0; j < 2; j++) { float vv = xs[row][sub * 2 + j]; s += vv; s2 += vv * vv; }
        #pragma unroll
        for (int off = 1; off < 32; off <<= 1) { s += __shfl_xor(s, off); s2 += __shfl_xor(s2, off); }
        float mu = s * (1.f / 64.f);
        float var = s2 * (1.f / 64.f) - mu * mu;
        float rs = rsqrtf(var + EPS);
        #pragma unroll
        for (int j = 0; j < 2; j++) {
            int d = sub * 2 + j;
            os[row][d] = (xs[row][d] - mu) * rs * g2[d] + bg2[d];
        }
    }
    __syncthreads();
    {
        float m1[8];
        #pragma unroll
        for (int i = 0; i < 8; i++) m1[i] = 0.f;
        for (int kk = 0; kk < 64; kk++) {
            float w = W1[kk * NF + t];
            #pragma unroll
            for (int i = 0; i < 8; i++) m1[i] += os[i][kk] * w;
        }
        float bb1 = b1[t];
        #pragma unroll
        for (int i = 0; i < 8; i++) as[i][t] = fmaxf(m1[i] + bb1, 0.f);
    }
    __syncthreads();
    {
        float m2[2] = {0.f, 0.f};
        for (int kk = 0; kk < 256; kk++) {
            float w = W2[kk * 64 + c];
            #pragma unroll
            for (int i = 0; i < 2; i++) m2[i] += as[rg * 2 + i][kk] * w;
        }
        float bias = b2m[c];
        #pragma unroll
        for (int i = 0; i < 2; i++) {
            int row = rg * 2 + i;
            xs[row][c] += m2[i] + bias;
        }
    }
    __syncthreads();

    if (last) {
        int row = t >> 5, sub = t & 31;
        float s = 0.f, s2 = 0.f;
        #pragma unroll
        for (int j = 0; j < 2; j++) { float vv = xs[row][sub * 2 + j]; s += vv; s2 += vv * vv; }
        #pragma unroll
        for (int off = 1; off < 32; off <<= 1) { s += __shfl_xor(s, off); s2 += __shfl_xor(s2, off); }
        float mu = s * (1.f / 64.f);
        float var = s2 * (1.f / 64.f) - mu * mu;
        float rs = rsqrtf(var + EPS);
        #pragma unroll
        for (int j = 0; j < 2; j++) {
            int d = sub * 2 + j;
            float val = (xs[row][d] - mu) * rs * lg[d] + lb[d];
            xfb[(r0 + row) * 64 + d] = __float2bfloat16(val);
        }
        return;
    }

    {
        #pragma unroll
        for (int i = 0; i < 2; i++) {
            int row = rg * 2 + i;
            x[(r0 + row) * 64 + c] = xs[row][c];
        }
    }
    {
        int row = t >> 5, sub = t & 31;
        float s = 0.f, s2 = 0.f;
        #pragma unroll
        for (int j = 0; j < 2; j++) { float vv = xs[row][sub * 2 + j]; s += vv; s2 += vv * vv; }
        #pragma unroll
        for (int off = 1; off < 32; off <<= 1) { s += __shfl_xor(s, off); s2 += __shfl_xor(s2, off); }
        float mu = s * (1.f / 64.f);
        float var = s2 * (1.f / 64.f) - mu * mu;
        float rs = rsqrtf(var + EPS);
        #pragma unroll
        for (int j = 0; j < 2; j++) {
            int d = sub * 2 + j;
            os[row][d] = (xs[row][d] - mu) * rs * g1n[d] + b1n[d];
        }
    }
    __syncthreads();
    {
        int head = c >> 4, sidx = c & 15;
        float aq[2], ak[2], av[2];
        #pragma unroll
        for (int i = 0; i < 2; i++) { aq[i] = 0.f; ak[i] = 0.f; av[i] = 0.f; }
        for (int kk = 0; kk < 64; kk++) {
            float wq = Wqn[(head * 64 + kk) * 16 + sidx];
            float wk = Wkn[(head * 64 + kk) * 16 + sidx];
            float wv = Wvn[(head * 64 + kk) * 16 + sidx];
            #pragma unroll
            for (int i = 0; i < 2; i++) {
                float h = os[rg * 2 + i][kk];
                aq[i] += h * wq; ak[i] += h * wk; av[i] += h * wv;
            }
        }
        #pragma unroll
        for (int i = 0; i < 2; i++) {
            int n = r0 + rg * 2 + i;
            int b = n >> 8, tt = n & 255;
            int oidx = ((b * NH + head) * NT + tt) * NHS + sidx;
            q[oidx] = __float2bfloat16(aq[i]);
            k[oidx] = __float2bfloat16(ak[i]);
            v[oidx] = __float2bfloat16(av[i]);
        }
    }
}

// ---------------- Whead [64][NV] f32 -> transposed bf16 [NVP][64] ----------------
__global__ __launch_bounds__(256) void k_convW(
        const float* __restrict__ Wh, __hip_bfloat16* __restrict__ whb) {
    __shared__ float w[64][65];
    int t = threadIdx.x;
    int n0 = blockIdx.x * 64;
    for (int i = t; i < 64 * 64; i += 256) {
        int k = i >> 6, c = i & 63;
        int n = n0 + c;
        w[k][c] = (n < NV) ? Wh[k * NV + n] : 0.f;
    }
    __syncthreads();
    int c = t >> 2, kq = t & 3;
    int n = n0 + c;
    union { __hip_bfloat16 h[16]; uint4 u[2]; } pk;
    #pragma unroll
    for (int j = 0; j < 16; j++)
        pk.h[j] = __float2bfloat16(w[kq * 16 + j][c]);
    uint4* dst = (uint4*)(whb + (size_t)n * 64 + kq * 16);
    dst[0] = pk.u[0];
    dst[1] = pk.u[1];
}

// ---------------- head GEMM: plain stores + LDS-transpose sum-exp reduce ----------------
// Shuffle chains (64 chained ds-ops/lane) replaced by 16 independent LDS writes
// + 16 contiguous reads per thread — less LDS-pipe pressure, more ILP.
__global__ __launch_bounds__(256) void k_head(
        const __hip_bfloat16* __restrict__ xfb, const __hip_bfloat16* __restrict__ whb,
        const float* __restrict__ bhead, float* __restrict__ out,
        float* __restrict__ wsum) {
    __shared__ float pes[4][64][17];
    __shared__ float ssm2[4][64];

    int i0 = blockIdx.x;
    int xcd = i0 & 7;
    int j  = i0 >> 3;
    int rb = j / CB_PER_XCD;
    int cb = xcd * CB_PER_XCD + (j - rb * CB_PER_XCD);

    int t = threadIdx.x;
    int w = t >> 6, l = t & 63;
    int lr = l & 15, lg = l >> 4;
    int r0 = rb * 64;
    int cw = cb * 256 + w * 64;
    int c4 = cw + lr * 4;

    bf16x8 a[4][2], b[4][2];
    {
        const __hip_bfloat16* ap = xfb + (size_t)(r0 + lr) * 64 + lg * 8;
        #pragma unroll
        for (int m = 0; m < 4; m++)
            #pragma unroll
            for (int ks = 0; ks < 2; ks++)
                a[m][ks] = *reinterpret_cast<const bf16x8*>(ap + m * 16 * 64 + ks * 32);
        const __hip_bfloat16* bp = whb + (size_t)c4 * 64 + lg * 8;
        #pragma unroll
        for (int n = 0; n < 4; n++)
            #pragma unroll
            for (int ks = 0; ks < 2; ks++)
                b[n][ks] = *reinterpret_cast<const bf16x8*>(bp + n * 64 + ks * 32);
    }

    f32x4 acc[4][4];
    #pragma unroll
    for (int m = 0; m < 4; m++)
        #pragma unroll
        for (int n = 0; n < 4; n++)
            #pragma unroll
            for (int j2 = 0; j2 < 4; j2++) acc[m][n][j2] = 0.f;

    #pragma unroll
    for (int ks = 0; ks < 2; ks++)
        #pragma unroll
        for (int m = 0; m < 4; m++)
            #pragma unroll
            for (int n = 0; n < 4; n++)
                acc[m][n] = __builtin_amdgcn_mfma_f32_16x16x32_bf16(a[m][ks], b[n][ks], acc[m][n], 0, 0, 0);

    bool all4 = (c4 + 3 < NV);
    float bias[4];
    bool  cok[4];
    if (all4) {
        float4 bv = *(const float4*)(bhead + c4);
        bias[0] = bv.x; bias[1] = bv.y; bias[2] = bv.z; bias[3] = bv.w;
        cok[0] = cok[1] = cok[2] = cok[3] = true;
    } else {
        #pragma unroll
        for (int n = 0; n < 4; n++) {
            int gc = c4 + n;
            cok[n] = (gc < NV);
            bias[n] = cok[n] ? bhead[gc] : 0.f;
        }
    }

    #pragma unroll
    for (int m = 0; m < 4; m++) {
        #pragma unroll
        for (int i = 0; i < 4; i++) {
            int rl = 4 * lg + i;
            int grow = r0 + m * 16 + rl;
            float vals[4];
            float e = 0.f;
            #pragma unroll
            for (int n = 0; n < 4; n++) {
                float v = acc[m][n][i] + bias[n];
                vals[n] = v;
                if (cok[n]) e += __expf(v);
            }
            pes[w][m * 16 + rl][lr] = e;
            float* dst = out + (size_t)grow * NV + c4;
            if (all4) {
                f32x4 vv = {vals[0], vals[1], vals[2], vals[3]};
                *(f32x4*)dst = vv;
            } else {
                #pragma unroll
                for (int n = 0; n < 4; n++)
                    if (cok[n]) dst[n] = vals[n];
            }
        }
    }

    __syncthreads();
    {
        int w2 = t >> 6, row = t & 63;
        float s = 0.f;
        #pragma unroll
        for (int k2 = 0; k2 < 16; k2++) s += pes[w2][row][k2];
        ssm2[w2][row] = s;
    }
    __syncthreads();
    if (t < 64)
        wsum[cb * NN + r0 + t] = ssm2[0][t] + ssm2[1][t] + ssm2[2][t] + ssm2[3][t];
}

// ---------------- loss stage 1 ----------------
__global__ void k_loss1(const float* __restrict__ wsum,
                        const float* __restrict__ out, const int* __restrict__ targets,
                        float* __restrict__ lp) {
    int row = blockIdx.x * blockDim.x + threadIdx.x;
    if (row >= NN) return;
    float S = 0.f;
    for (int cb = 0; cb < NCB2; cb++)
        S += wsum[cb * NN + row];
    float lse = logf(S);
    int tg = targets[row];
    float lt = out[(size_t)row * NV + tg];
    lp[row] = lt - lse;
}

// ---------------- loss stage 2 ----------------
__global__ void k_loss2(const float* __restrict__ lp, float* __restrict__ out) {
    __shared__ float red[4];
    int t = threadIdx.x;
    float s = 0.f;
    for (int i = t; i < NN; i += 256) s += lp[i];
    for (int off = 1; off < 64; off <<= 1) s += __shfl_xor(s, off);
    if ((t & 63) == 0) red[t >> 6] = s;
    __syncthreads();
    if (t == 0) {
        float tot = red[0] + red[1] + red[2] + red[3];
        out[LOGITS] = -tot / (float)NN;
    }
}

extern "C" void kernel_launch(void* const* d_in, const int* in_sizes, int n_in,
                              void* d_out, int out_size, void* d_ws, size_t ws_size,
                              hipStream_t stream) {
    const int*   idx     = (const int*)d_in[0];
    const int*   targets = (const int*)d_in[1];
    const float* tok     = (const float*)d_in[2];
    const float* pos     = (const float*)d_in[3];
    const float* Wq      = (const float*)d_in[4];
    const float* Wk      = (const float*)d_in[5];
    const float* Wv      = (const float*)d_in[6];
    const float* Wo      = (const float*)d_in[7];
    const float* bo      = (const float*)d_in[8];
    const float* ln1g    = (const float*)d_in[9];
    const float* ln1b    = (const float*)d_in[10];
    const float* ln2g    = (const float*)d_in[11];
    const float* ln2b    = (const float*)d_in[12];
    const float* W1      = (const float*)d_in[13];
    const float* b1      = (const float*)d_in[14];
    const float* W2      = (const float*)d_in[15];
    const float* b2      = (const float*)d_in[16];
    const float* lnfg    = (const float*)d_in[17];
    const float* lnfb    = (const float*)d_in[18];
    const float* Wh      = (const float*)d_in[19];
    const float* bhead   = (const float*)d_in[20];

    float* ws = (float*)d_ws;
    float* x  = ws + X_OFF;
    __hip_bfloat16* q = (__hip_bfloat16*)(ws + Q_OFF);
    __hip_bfloat16* k = (__hip_bfloat16*)(ws + K_OFF);
    __hip_bfloat16* v = (__hip_bfloat16*)(ws + V_OFF);
    float* o  = ws + O_OFF;
    __hip_bfloat16* xfb = (__hip_bfloat16*)(ws + XFB_OFF);
    float* wsm = ws + WS2_OFF;
    __hip_bfloat16* whb = (__hip_bfloat16*)(ws + WHB_OFF);
    float* lp  = ws + LP_OFF;
    float* out = (float*)d_out;

    k_convW<<<NVP / 64, 256, 0, stream>>>(Wh, whb);

    k_ln_qkv<<<NN / 16, 256, 0, stream>>>(x, ln1g, ln1b, Wq, Wk, Wv, q, k, v,
                                          idx, tok, pos);

    for (int l = 0; l < NL; l++) {
        int last = (l == NL - 1) ? 1 : 0;
        int ln = last ? l : l + 1;
        k_attn<<<NB * NH * 4, 256, 0, stream>>>(q, k, v, o);
        k_post<<<NN / 8, 256, 0, stream>>>(o, Wo + l * ND * ND, bo + l * ND,
                                           ln2g + l * ND, ln2b + l * ND,
                                           W1 + l * ND * NF, b1 + l * NF,
                                           W2 + l * NF * ND, b2 + l * ND, x,
                                           ln1g + ln * ND, ln1b + ln * ND,
                                           Wq + ln * NH * ND * NHS,
                                           Wk + ln * NH * ND * NHS,
                                           Wv + ln * NH * ND * NHS,
                                           q, k, v,
                                           lnfg, lnfb, xfb, last);
    }

    k_head<<<NCB2 * RB_N, 256, 0, stream>>>(xfb, whb, bhead, out, wsm);

    k_loss1<<<NN / 256, 256, 0, stream>>>(wsm, out, targets, lp);
    k_loss2<<<1, 256, 0, stream>>>(lp, out);
}